// Round 8
// baseline (128.289 us; speedup 1.0000x reference)
//
#include <hip/hip_runtime.h>
#include <math.h>

#define B_ 4
#define C_ 32
#define H_ 256
#define W_ 256
#define HW_ (H_ * W_)
#define K_ 9
#define TX 32
#define TY 4
#define HX 34              // TX + 2
#define HY 6               // TY + 2
#define HCH (HX * HY)      // 204 halo positions
#define NPAIR 16           // 32 channels as 16 f16x2 pairs
#define NQUAD 8            // 8 quads of 2 pairs (4 channels)
#define HWORDS (HCH * NPAIR)   // 3264 h2v words = 12.75 KB
#define EPS_ 1e-12f

typedef _Float16 h2v __attribute__((ext_vector_type(2)));
typedef _Float16 h4v __attribute__((ext_vector_type(4)));

#if defined(__has_builtin)
#if __has_builtin(__builtin_amdgcn_fdot2)
#define HAVE_FDOT2 1
#endif
#endif

// R7 geometry (256 thr, 32x4 tile, 2 thr/pixel channel-halves, 12.75 KB LDS,
// grid 2048 = exactly 8 blocks/CU, one round) with:
//  - fe held in 16 fp32 regs across BOTH passes (loaded before staging so the
//    latency hides under the staging phase). Live ~50 < cap 64 (R2: 60+/84
//    spilled; R5: 35/32 spilled — margin matters in BOTH directions).
//  - LDS layout [quad][pos][2 words]: tap reads are ds_read_b64 via h4 view,
//    72 DS instrs/thread instead of 144. Wave b64 = 512B = 4 bank-cycle floor.
//  - v_dot2_f32_f16 for pass-1 stats (f32 accumulate, guarded fallback).
__global__ __launch_bounds__(256, 8) void asfr_kernel(const float* __restrict__ fe,
                                                      const float* __restrict__ fu,
                                                      float* __restrict__ out) {
    __shared__ h2v smem[HWORDS];
    h4v* smem4 = reinterpret_cast<h4v*>(smem);
    const int t = threadIdx.x;
    const int bx = blockIdx.x & 7;           // W_/TX = 8
    const int by = (blockIdx.x >> 3) & 63;   // H_/TY = 64
    const int b  = blockIdx.x >> 9;
    const int w0 = bx * TX, h0 = by * TY;

    const int x = t & 31;            // pixel x
    const int half = (t >> 5) & 1;   // channel half
    const int y = t >> 6;            // pixel y (wave id)
    const int c0 = half << 4;        // first channel of this half
    const int pxoff = b * (C_ * HW_) + (h0 + y) * W_ + (w0 + x);

    // fe channel vector (this half) into registers — issued before staging,
    // its HBM latency hides under the staging loads.
    float fereg[16];
#pragma unroll
    for (int cc = 0; cc < 16; ++cc) fereg[cc] = fe[pxoff + (c0 + cc) * HW_];

    // stage fu halo as f16 pairs, layout word = quad*408 + 2*pos + (pair&1)
    const float* fub = fu + b * (C_ * HW_);
#pragma unroll 4
    for (int j = 0; j < 12; ++j) {
        int i = t + j * 256;
        int pair = i / HCH;
        int pos = i - pair * HCH;
        int r = pos / HX;
        int col = pos - r * HX;
        int hh = h0 - 1 + r;
        int ww = w0 - 1 + col;
        float a = 0.f, bb = 0.f;
        if (((unsigned)hh < (unsigned)H_) && ((unsigned)ww < (unsigned)W_)) {
            const float* p = fub + (2 * pair) * HW_ + hh * W_ + ww;
            a = p[0]; bb = p[HW_];
        }
        h2v v = {(_Float16)a, (_Float16)bb};
        smem[(pair >> 1) * (2 * HCH) + 2 * pos + (pair & 1)] = v;
    }
    {   // tail: i = t + 12*256, valid for t < 192
        int i = t + 3072;
        if (i < HWORDS) {
            int pair = i / HCH;
            int pos = i - pair * HCH;
            int r = pos / HX;
            int col = pos - r * HX;
            int hh = h0 - 1 + r;
            int ww = w0 - 1 + col;
            float a = 0.f, bb = 0.f;
            if (((unsigned)hh < (unsigned)H_) && ((unsigned)ww < (unsigned)W_)) {
                const float* p = fub + (2 * pair) * HW_ + hh * W_ + ww;
                a = p[0]; bb = p[HW_];
            }
            h2v v = {(_Float16)a, (_Float16)bb};
            smem[(pair >> 1) * (2 * HCH) + 2 * pos + (pair & 1)] = v;
        }
    }
    __syncthreads();

    const int hc = (y + 1) * HX + (x + 1);
    const int koff[K_] = {-HX - 1, -HX, -HX + 1, -1, 0, 1, HX - 1, HX, HX + 1};
    const int q0 = half << 2;        // first quad of this half

    float fsq = 0.f;
#pragma unroll
    for (int cc = 0; cc < 16; ++cc) fsq = fmaf(fereg[cc], fereg[cc], fsq);

    h2v fe2[8];
#pragma unroll
    for (int pp = 0; pp < 8; ++pp) {
        h2v v = {(_Float16)fereg[2 * pp], (_Float16)fereg[2 * pp + 1]};
        fe2[pp] = v;
    }

    float dot[K_], psq[K_];
#pragma unroll
    for (int k = 0; k < K_; ++k) { dot[k] = 0.f; psq[k] = 0.f; }
#if !defined(HAVE_FDOT2)
    h2v da[K_], qa[K_];
    const h2v zz = {(_Float16)0, (_Float16)0};
#pragma unroll
    for (int k = 0; k < K_; ++k) { da[k] = zz; qa[k] = zz; }
#endif

    // Pass 1: per-k stats; one ds_read_b64 per tap per quad (2 pairs = 4 ch)
#pragma unroll
    for (int j = 0; j < 4; ++j) {
        const int qb = (q0 + j) * HCH + hc;   // h4 index base
        h2v fA = fe2[2 * j], fB = fe2[2 * j + 1];
#pragma unroll
        for (int k = 0; k < K_; ++k) {
            h4v p4 = smem4[qb + koff[k]];
            h2v pA = __builtin_shufflevector(p4, p4, 0, 1);
            h2v pB = __builtin_shufflevector(p4, p4, 2, 3);
#if defined(HAVE_FDOT2)
            dot[k] = __builtin_amdgcn_fdot2(pA, fA, dot[k], false);
            dot[k] = __builtin_amdgcn_fdot2(pB, fB, dot[k], false);
            psq[k] = __builtin_amdgcn_fdot2(pA, pA, psq[k], false);
            psq[k] = __builtin_amdgcn_fdot2(pB, pB, psq[k], false);
#else
            da[k] += pA * fA;
            da[k] += pB * fB;
            qa[k] += pA * pA;
            qa[k] += pB * pB;
#endif
        }
    }
#if !defined(HAVE_FDOT2)
#pragma unroll
    for (int k = 0; k < K_; ++k) {
        dot[k] = (float)da[k][0] + (float)da[k][1];
        psq[k] = (float)qa[k][0] + (float)qa[k][1];
    }
#endif

    // combine halves: lanes l and l^32 hold the two channel-halves of one pixel
#pragma unroll
    for (int k = 0; k < K_; ++k) {
        dot[k] += __shfl_xor(dot[k], 32);
        psq[k] += __shfl_xor(psq[k], 32);
    }
    fsq += __shfl_xor(fsq, 32);

    float nf = fmaxf(sqrtf(fsq), EPS_);
    float cosv[K_], negd[K_];
#pragma unroll
    for (int k = 0; k < K_; ++k) {
        float np = fmaxf(sqrtf(psq[k]), EPS_);
        cosv[k] = __fdividef(dot[k], np * nf);
        float dsq = fmaxf(psq[k] - 2.f * dot[k] + fsq, 0.f);   // ||p-f||^2
        negd[k] = -sqrtf(dsq);
    }

    float m1 = cosv[0], m2 = negd[0];
#pragma unroll
    for (int k = 1; k < K_; ++k) { m1 = fmaxf(m1, cosv[k]); m2 = fmaxf(m2, negd[k]); }
    float s1 = 0.f, s2 = 0.f, e1[K_], e2[K_];
#pragma unroll
    for (int k = 0; k < K_; ++k) {
        e1[k] = __expf(cosv[k] - m1);
        e2[k] = __expf(negd[k] - m2);
        s1 += e1[k]; s2 += e2[k];
    }
    float r1 = __fdividef(0.5f, s1), r2 = __fdividef(0.5f, s2);
    h2v w2[K_];
#pragma unroll
    for (int k = 0; k < K_; ++k) {
        float wk = fmaf(e1[k], r1, e2[k] * r2);
        _Float16 wh = (_Float16)wk;
        h2v tmp = {wh, wh};
        w2[k] = tmp;
    }

    // Pass 2: packed weighted gather (b64 taps) + fp32 residual from registers
#pragma unroll
    for (int j = 0; j < 4; ++j) {
        const int qb = (q0 + j) * HCH + hc;
        h2v accA = {(_Float16)0, (_Float16)0};
        h2v accB = {(_Float16)0, (_Float16)0};
#pragma unroll
        for (int k = 0; k < K_; ++k) {
            h4v p4 = smem4[qb + koff[k]];
            h2v pA = __builtin_shufflevector(p4, p4, 0, 1);
            h2v pB = __builtin_shufflevector(p4, p4, 2, 3);
            accA += w2[k] * pA;   // v_pk_fma_f16
            accB += w2[k] * pB;
        }
        const int cg = c0 + 4 * j;
        out[pxoff + (cg + 0) * HW_] = fereg[4 * j + 0] + (float)accA[0];
        out[pxoff + (cg + 1) * HW_] = fereg[4 * j + 1] + (float)accA[1];
        out[pxoff + (cg + 2) * HW_] = fereg[4 * j + 2] + (float)accB[0];
        out[pxoff + (cg + 3) * HW_] = fereg[4 * j + 3] + (float)accB[1];
    }
}

extern "C" void kernel_launch(void* const* d_in, const int* in_sizes, int n_in,
                              void* d_out, int out_size, void* d_ws, size_t ws_size,
                              hipStream_t stream) {
    const float* fe = (const float*)d_in[0];
    const float* fu = (const float*)d_in[1];
    float* out = (float*)d_out;
    dim3 grid((W_ / TX) * (H_ / TY) * B_), block(256);  // 2048 blocks = 8/CU exact
    hipLaunchKernelGGL(asfr_kernel, grid, block, 0, stream, fe, fu, out);
}

// Round 9
// 104.576 us; speedup vs baseline: 1.2267x; 1.2267x over previous
//
#include <hip/hip_runtime.h>
#include <math.h>

#define B_ 4
#define C_ 32
#define H_ 256
#define W_ 256
#define HW_ (H_ * W_)
#define K_ 9
#define TX 32
#define TY 8
#define HX 34              // TX + 2
#define HY 10              // TY + 2
#define HCH (HX * HY)      // 340 halo positions
#define NPAIR 16           // 32 channels as 16 f16x2 pairs
#define NPX (TX * TY)      // 256 pixels per tile
#define FUW (HCH * NPAIR)  // 5440 h2v words (21.25 KB) fu halo
#define FEW (NPX * NPAIR)  // 4096 h2v words (16 KB) fe tile
#define EPS_ 1e-12f

typedef _Float16 h2v __attribute__((ext_vector_type(2)));
typedef _Float16 h4v __attribute__((ext_vector_type(4)));

#if defined(__has_builtin)
#if __has_builtin(__builtin_amdgcn_fdot2)
#define HAVE_FDOT2 1
#endif
#endif

// 512 thr = 8 waves, 32x8 tile, 2 thr/pixel (channel halves). LDS 37.25 KB ->
// exactly 4 blocks/CU = 32 waves/CU; grid 1024 = exact 4/CU fill, no tail.
// fe staged in LDS as f16 quads (NOT registers -- R2/R5/R8 all spilled when
// fp32 arrays lived across the softmax; cross-pass live state here is ~25 regs).
// All taps are ds_read_b64 (4 channels/read): 80 reads/thread vs R7's 144+32gl.
// fe read from HBM once (-32 MB vs R7). fdot2 = f32 accumulate in one VOP3P.
__global__ __launch_bounds__(512, 8) void asfr_kernel(const float* __restrict__ fe,
                                                      const float* __restrict__ fu,
                                                      float* __restrict__ out) {
    __shared__ alignas(16) h2v smem[FUW + FEW];
    h4v* fu4 = reinterpret_cast<h4v*>(smem);            // [quad][HCH] h4
    h4v* fe4 = reinterpret_cast<h4v*>(smem + FUW);      // [quad][NPX] h4
    const int t = threadIdx.x;
    const int bx = blockIdx.x & 7;           // W_/TX = 8
    const int by = (blockIdx.x >> 3) & 31;   // H_/TY = 32
    const int b  = blockIdx.x >> 8;
    const int w0 = bx * TX, h0 = by * TY;

    const float* fub = fu + b * (C_ * HW_);
    const float* feb = fe + b * (C_ * HW_);

    // ---- stage fu halo as f16 quads: word = (pair>>1)*2*HCH + 2*pos + (pair&1)
#pragma unroll 5
    for (int j = 0; j < 10; ++j) {
        int i = t + j * 512;
        int pair = i / HCH;
        int pos = i - pair * HCH;
        int r = pos / HX;
        int col = pos - r * HX;
        int hh = h0 - 1 + r;
        int ww = w0 - 1 + col;
        float a = 0.f, bb = 0.f;
        if (((unsigned)hh < (unsigned)H_) && ((unsigned)ww < (unsigned)W_)) {
            const float* p = fub + (2 * pair) * HW_ + hh * W_ + ww;
            a = p[0]; bb = p[HW_];
        }
        h2v v = {(_Float16)a, (_Float16)bb};
        smem[(pair >> 1) * (2 * HCH) + 2 * pos + (pair & 1)] = v;
    }
    if (t < FUW - 5120) {   // tail 320
        int i = t + 5120;
        int pair = i / HCH;
        int pos = i - pair * HCH;
        int r = pos / HX;
        int col = pos - r * HX;
        int hh = h0 - 1 + r;
        int ww = w0 - 1 + col;
        float a = 0.f, bb = 0.f;
        if (((unsigned)hh < (unsigned)H_) && ((unsigned)ww < (unsigned)W_)) {
            const float* p = fub + (2 * pair) * HW_ + hh * W_ + ww;
            a = p[0]; bb = p[HW_];
        }
        h2v v = {(_Float16)a, (_Float16)bb};
        smem[(pair >> 1) * (2 * HCH) + 2 * pos + (pair & 1)] = v;
    }

    // ---- stage fe tile (no halo): word = FUW + (pair>>1)*2*NPX + 2*px + (pair&1)
#pragma unroll 4
    for (int j = 0; j < 8; ++j) {
        int i = t + j * 512;
        int pair = i >> 8;          // i / NPX
        int px = i & (NPX - 1);
        int hh = h0 + (px >> 5);
        int ww = w0 + (px & 31);
        const float* p = feb + (2 * pair) * HW_ + hh * W_ + ww;
        h2v v = {(_Float16)p[0], (_Float16)p[HW_]};
        smem[FUW + (pair >> 1) * (2 * NPX) + 2 * px + (pair & 1)] = v;
    }
    __syncthreads();

    const int x = t & 31;            // pixel x
    const int half = (t >> 5) & 1;   // channel half
    const int y = t >> 6;            // pixel y (0..7)
    const int q0 = half << 2;        // quads 0..3 or 4..7 (channels 4q..4q+3)
    const int pxl = (y << 5) + x;    // local pixel index
    const int pxoff = b * (C_ * HW_) + (h0 + y) * W_ + (w0 + x);
    const int hc = (y + 1) * HX + (x + 1);
    const int koff[K_] = {-HX - 1, -HX, -HX + 1, -1, 0, 1, HX - 1, HX, HX + 1};

    float dot[K_], psq[K_];
#pragma unroll
    for (int k = 0; k < K_; ++k) { dot[k] = 0.f; psq[k] = 0.f; }
    float fsq = 0.f;

    // Pass 1: per-k stats; fu and fe both from LDS via b64 quad reads
#pragma unroll
    for (int j = 0; j < 4; ++j) {
        const int q = q0 + j;
        h4v fq = fe4[q * NPX + pxl];
        h2v fA = __builtin_shufflevector(fq, fq, 0, 1);
        h2v fB = __builtin_shufflevector(fq, fq, 2, 3);
#if defined(HAVE_FDOT2)
        fsq = __builtin_amdgcn_fdot2(fA, fA, fsq, false);
        fsq = __builtin_amdgcn_fdot2(fB, fB, fsq, false);
#else
        fsq += (float)fA[0]*(float)fA[0] + (float)fA[1]*(float)fA[1]
             + (float)fB[0]*(float)fB[0] + (float)fB[1]*(float)fB[1];
#endif
        const int qb = q * HCH + hc;
#pragma unroll
        for (int k = 0; k < K_; ++k) {
            h4v p4 = fu4[qb + koff[k]];
            h2v pA = __builtin_shufflevector(p4, p4, 0, 1);
            h2v pB = __builtin_shufflevector(p4, p4, 2, 3);
#if defined(HAVE_FDOT2)
            dot[k] = __builtin_amdgcn_fdot2(pA, fA, dot[k], false);
            dot[k] = __builtin_amdgcn_fdot2(pB, fB, dot[k], false);
            psq[k] = __builtin_amdgcn_fdot2(pA, pA, psq[k], false);
            psq[k] = __builtin_amdgcn_fdot2(pB, pB, psq[k], false);
#else
            dot[k] += (float)pA[0]*(float)fA[0] + (float)pA[1]*(float)fA[1]
                    + (float)pB[0]*(float)fB[0] + (float)pB[1]*(float)fB[1];
            psq[k] += (float)pA[0]*(float)pA[0] + (float)pA[1]*(float)pA[1]
                    + (float)pB[0]*(float)pB[0] + (float)pB[1]*(float)pB[1];
#endif
        }
    }

    // combine halves: lanes l and l^32 hold the two channel-halves of one pixel
#pragma unroll
    for (int k = 0; k < K_; ++k) {
        dot[k] += __shfl_xor(dot[k], 32);
        psq[k] += __shfl_xor(psq[k], 32);
    }
    fsq += __shfl_xor(fsq, 32);

    float nf = fmaxf(sqrtf(fsq), EPS_);
    float cosv[K_], negd[K_];
#pragma unroll
    for (int k = 0; k < K_; ++k) {
        float np = fmaxf(sqrtf(psq[k]), EPS_);
        cosv[k] = __fdividef(dot[k], np * nf);
        float dsq = fmaxf(psq[k] - 2.f * dot[k] + fsq, 0.f);   // ||p-f||^2
        negd[k] = -sqrtf(dsq);
    }

    float m1 = cosv[0], m2 = negd[0];
#pragma unroll
    for (int k = 1; k < K_; ++k) { m1 = fmaxf(m1, cosv[k]); m2 = fmaxf(m2, negd[k]); }
    float s1 = 0.f, s2 = 0.f, e1[K_], e2[K_];
#pragma unroll
    for (int k = 0; k < K_; ++k) {
        e1[k] = __expf(cosv[k] - m1);
        e2[k] = __expf(negd[k] - m2);
        s1 += e1[k]; s2 += e2[k];
    }
    float r1 = __fdividef(0.5f, s1), r2 = __fdividef(0.5f, s2);
    h2v w2[K_];
#pragma unroll
    for (int k = 0; k < K_; ++k) {
        float wk = fmaf(e1[k], r1, e2[k] * r2);
        _Float16 wh = (_Float16)wk;
        h2v tmp = {wh, wh};
        w2[k] = tmp;
    }

    // Pass 2: packed weighted gather (b64 taps) + residual from LDS fe
#pragma unroll
    for (int j = 0; j < 4; ++j) {
        const int q = q0 + j;
        const int qb = q * HCH + hc;
        h2v accA = {(_Float16)0, (_Float16)0};
        h2v accB = {(_Float16)0, (_Float16)0};
#pragma unroll
        for (int k = 0; k < K_; ++k) {
            h4v p4 = fu4[qb + koff[k]];
            h2v pA = __builtin_shufflevector(p4, p4, 0, 1);
            h2v pB = __builtin_shufflevector(p4, p4, 2, 3);
            accA += w2[k] * pA;   // v_pk_fma_f16
            accB += w2[k] * pB;
        }
        h4v fq = fe4[q * NPX + pxl];
        const int cg = 4 * q;
        out[pxoff + (cg + 0) * HW_] = (float)fq[0] + (float)accA[0];
        out[pxoff + (cg + 1) * HW_] = (float)fq[1] + (float)accA[1];
        out[pxoff + (cg + 2) * HW_] = (float)fq[2] + (float)accB[0];
        out[pxoff + (cg + 3) * HW_] = (float)fq[3] + (float)accB[1];
    }
}

extern "C" void kernel_launch(void* const* d_in, const int* in_sizes, int n_in,
                              void* d_out, int out_size, void* d_ws, size_t ws_size,
                              hipStream_t stream) {
    const float* fe = (const float*)d_in[0];
    const float* fu = (const float*)d_in[1];
    float* out = (float*)d_out;
    dim3 grid((W_ / TX) * (H_ / TY) * B_), block(512);  // 1024 blocks = 4/CU exact
    hipLaunchKernelGGL(asfr_kernel, grid, block, 0, stream, fe, fu, out);
}

// Round 10
// 38.679 us; speedup vs baseline: 3.3168x; 2.7037x over previous
//
#include <hip/hip_runtime.h>
#include <math.h>

#define B_ 4
#define C_ 32
#define H_ 256
#define W_ 256
#define HW_ (H_ * W_)
#define K_ 9
#define TX 32
#define TY 8
#define HX 34              // TX + 2
#define HY 10              // TY + 2
#define HCH (HX * HY)      // 340 halo positions
#define NPAIR 16           // 32 channels as 16 f16x2 pairs
#define NPX (TX * TY)      // 256 pixels per tile
#define FUW (HCH * NPAIR)  // 5440 h2v words (21.25 KB) fu halo
#define FEW (NPX * NPAIR)  // 4096 h2v words (16 KB) fe tile
#define EPS_ 1e-12f

typedef _Float16 h2v __attribute__((ext_vector_type(2)));
typedef _Float16 h4v __attribute__((ext_vector_type(4)));

#if defined(__has_builtin)
#if __has_builtin(__builtin_amdgcn_fdot2)
#define HAVE_FDOT2 1
#endif
#endif

// R9 structure, launch-bounds fix only. Spill ledger: (256,8)->VGPR24 clean,
// (256,6)->40 clean, (1024,8)->32 SPILL, (512,8)->32 SPILL. Consistent with
// hipcc using CUDA semantics for arg2 (min BLOCKS/CU): (512,8) = 64 waves/CU
// -> cap 32 -> spill. (512,4) = 32 waves/CU -> cap 64 under blocks-semantics,
// 128 under waves/EU-semantics: safe either way. Occupancy is governed by the
// real resources anyway: LDS 37.25 KB -> 4 blocks/CU = 32 waves/CU = 100%,
// grid 1024 = exact fill, no tail.
__global__ __launch_bounds__(512, 4) void asfr_kernel(const float* __restrict__ fe,
                                                      const float* __restrict__ fu,
                                                      float* __restrict__ out) {
    __shared__ alignas(16) h2v smem[FUW + FEW];
    h4v* fu4 = reinterpret_cast<h4v*>(smem);            // [quad][HCH] h4
    h4v* fe4 = reinterpret_cast<h4v*>(smem + FUW);      // [quad][NPX] h4
    const int t = threadIdx.x;
    const int bx = blockIdx.x & 7;           // W_/TX = 8
    const int by = (blockIdx.x >> 3) & 31;   // H_/TY = 32
    const int b  = blockIdx.x >> 8;
    const int w0 = bx * TX, h0 = by * TY;

    const float* fub = fu + b * (C_ * HW_);
    const float* feb = fe + b * (C_ * HW_);

    // ---- stage fu halo as f16 quads: word = (pair>>1)*2*HCH + 2*pos + (pair&1)
#pragma unroll 5
    for (int j = 0; j < 10; ++j) {
        int i = t + j * 512;
        int pair = i / HCH;
        int pos = i - pair * HCH;
        int r = pos / HX;
        int col = pos - r * HX;
        int hh = h0 - 1 + r;
        int ww = w0 - 1 + col;
        float a = 0.f, bb = 0.f;
        if (((unsigned)hh < (unsigned)H_) && ((unsigned)ww < (unsigned)W_)) {
            const float* p = fub + (2 * pair) * HW_ + hh * W_ + ww;
            a = p[0]; bb = p[HW_];
        }
        h2v v = {(_Float16)a, (_Float16)bb};
        smem[(pair >> 1) * (2 * HCH) + 2 * pos + (pair & 1)] = v;
    }
    if (t < FUW - 5120) {   // tail 320
        int i = t + 5120;
        int pair = i / HCH;
        int pos = i - pair * HCH;
        int r = pos / HX;
        int col = pos - r * HX;
        int hh = h0 - 1 + r;
        int ww = w0 - 1 + col;
        float a = 0.f, bb = 0.f;
        if (((unsigned)hh < (unsigned)H_) && ((unsigned)ww < (unsigned)W_)) {
            const float* p = fub + (2 * pair) * HW_ + hh * W_ + ww;
            a = p[0]; bb = p[HW_];
        }
        h2v v = {(_Float16)a, (_Float16)bb};
        smem[(pair >> 1) * (2 * HCH) + 2 * pos + (pair & 1)] = v;
    }

    // ---- stage fe tile (no halo): word = FUW + (pair>>1)*2*NPX + 2*px + (pair&1)
#pragma unroll 4
    for (int j = 0; j < 8; ++j) {
        int i = t + j * 512;
        int pair = i >> 8;          // i / NPX
        int px = i & (NPX - 1);
        int hh = h0 + (px >> 5);
        int ww = w0 + (px & 31);
        const float* p = feb + (2 * pair) * HW_ + hh * W_ + ww;
        h2v v = {(_Float16)p[0], (_Float16)p[HW_]};
        smem[FUW + (pair >> 1) * (2 * NPX) + 2 * px + (pair & 1)] = v;
    }
    __syncthreads();

    const int x = t & 31;            // pixel x
    const int half = (t >> 5) & 1;   // channel half
    const int y = t >> 6;            // pixel y (0..7)
    const int q0 = half << 2;        // quads 0..3 or 4..7 (channels 4q..4q+3)
    const int pxl = (y << 5) + x;    // local pixel index
    const int pxoff = b * (C_ * HW_) + (h0 + y) * W_ + (w0 + x);
    const int hc = (y + 1) * HX + (x + 1);
    const int koff[K_] = {-HX - 1, -HX, -HX + 1, -1, 0, 1, HX - 1, HX, HX + 1};

    float dot[K_], psq[K_];
#pragma unroll
    for (int k = 0; k < K_; ++k) { dot[k] = 0.f; psq[k] = 0.f; }
    float fsq = 0.f;

    // Pass 1: per-k stats; fu and fe both from LDS via b64 quad reads
#pragma unroll
    for (int j = 0; j < 4; ++j) {
        const int q = q0 + j;
        h4v fq = fe4[q * NPX + pxl];
        h2v fA = __builtin_shufflevector(fq, fq, 0, 1);
        h2v fB = __builtin_shufflevector(fq, fq, 2, 3);
#if defined(HAVE_FDOT2)
        fsq = __builtin_amdgcn_fdot2(fA, fA, fsq, false);
        fsq = __builtin_amdgcn_fdot2(fB, fB, fsq, false);
#else
        fsq += (float)fA[0]*(float)fA[0] + (float)fA[1]*(float)fA[1]
             + (float)fB[0]*(float)fB[0] + (float)fB[1]*(float)fB[1];
#endif
        const int qb = q * HCH + hc;
#pragma unroll
        for (int k = 0; k < K_; ++k) {
            h4v p4 = fu4[qb + koff[k]];
            h2v pA = __builtin_shufflevector(p4, p4, 0, 1);
            h2v pB = __builtin_shufflevector(p4, p4, 2, 3);
#if defined(HAVE_FDOT2)
            dot[k] = __builtin_amdgcn_fdot2(pA, fA, dot[k], false);
            dot[k] = __builtin_amdgcn_fdot2(pB, fB, dot[k], false);
            psq[k] = __builtin_amdgcn_fdot2(pA, pA, psq[k], false);
            psq[k] = __builtin_amdgcn_fdot2(pB, pB, psq[k], false);
#else
            dot[k] += (float)pA[0]*(float)fA[0] + (float)pA[1]*(float)fA[1]
                    + (float)pB[0]*(float)fB[0] + (float)pB[1]*(float)fB[1];
            psq[k] += (float)pA[0]*(float)pA[0] + (float)pA[1]*(float)pA[1]
                    + (float)pB[0]*(float)pB[0] + (float)pB[1]*(float)pB[1];
#endif
        }
    }

    // combine halves: lanes l and l^32 hold the two channel-halves of one pixel
#pragma unroll
    for (int k = 0; k < K_; ++k) {
        dot[k] += __shfl_xor(dot[k], 32);
        psq[k] += __shfl_xor(psq[k], 32);
    }
    fsq += __shfl_xor(fsq, 32);

    float nf = fmaxf(sqrtf(fsq), EPS_);
    float cosv[K_], negd[K_];
#pragma unroll
    for (int k = 0; k < K_; ++k) {
        float np = fmaxf(sqrtf(psq[k]), EPS_);
        cosv[k] = __fdividef(dot[k], np * nf);
        float dsq = fmaxf(psq[k] - 2.f * dot[k] + fsq, 0.f);   // ||p-f||^2
        negd[k] = -sqrtf(dsq);
    }

    float m1 = cosv[0], m2 = negd[0];
#pragma unroll
    for (int k = 1; k < K_; ++k) { m1 = fmaxf(m1, cosv[k]); m2 = fmaxf(m2, negd[k]); }
    float s1 = 0.f, s2 = 0.f, e1[K_], e2[K_];
#pragma unroll
    for (int k = 0; k < K_; ++k) {
        e1[k] = __expf(cosv[k] - m1);
        e2[k] = __expf(negd[k] - m2);
        s1 += e1[k]; s2 += e2[k];
    }
    float r1 = __fdividef(0.5f, s1), r2 = __fdividef(0.5f, s2);
    h2v w2[K_];
#pragma unroll
    for (int k = 0; k < K_; ++k) {
        float wk = fmaf(e1[k], r1, e2[k] * r2);
        _Float16 wh = (_Float16)wk;
        h2v tmp = {wh, wh};
        w2[k] = tmp;
    }

    // Pass 2: packed weighted gather (b64 taps) + residual from LDS fe
#pragma unroll
    for (int j = 0; j < 4; ++j) {
        const int q = q0 + j;
        const int qb = q * HCH + hc;
        h2v accA = {(_Float16)0, (_Float16)0};
        h2v accB = {(_Float16)0, (_Float16)0};
#pragma unroll
        for (int k = 0; k < K_; ++k) {
            h4v p4 = fu4[qb + koff[k]];
            h2v pA = __builtin_shufflevector(p4, p4, 0, 1);
            h2v pB = __builtin_shufflevector(p4, p4, 2, 3);
            accA += w2[k] * pA;   // v_pk_fma_f16
            accB += w2[k] * pB;
        }
        h4v fq = fe4[q * NPX + pxl];
        const int cg = 4 * q;
        out[pxoff + (cg + 0) * HW_] = (float)fq[0] + (float)accA[0];
        out[pxoff + (cg + 1) * HW_] = (float)fq[1] + (float)accA[1];
        out[pxoff + (cg + 2) * HW_] = (float)fq[2] + (float)accB[0];
        out[pxoff + (cg + 3) * HW_] = (float)fq[3] + (float)accB[1];
    }
}

extern "C" void kernel_launch(void* const* d_in, const int* in_sizes, int n_in,
                              void* d_out, int out_size, void* d_ws, size_t ws_size,
                              hipStream_t stream) {
    const float* fe = (const float*)d_in[0];
    const float* fu = (const float*)d_in[1];
    float* out = (float*)d_out;
    dim3 grid((W_ / TX) * (H_ / TY) * B_), block(512);  // 1024 blocks = 4/CU exact
    hipLaunchKernelGGL(asfr_kernel, grid, block, 0, stream, fe, fu, out);
}

// Round 12
// 35.124 us; speedup vs baseline: 3.6525x; 1.1012x over previous
//
#include <hip/hip_runtime.h>
#include <math.h>

#define B_ 4
#define C_ 32
#define H_ 256
#define W_ 256
#define HW_ (H_ * W_)
#define K_ 9
#define TX 32
#define TY 8
#define HX 34              // TX + 2
#define HY 10              // TY + 2
#define HCH (HX * HY)      // 340 halo positions
#define NPX (TX * TY)      // 256 pixels per tile
#define NOCT 4             // 32 channels = 4 octs of 8
#define FUH8 (NOCT * HCH)  // 1360 h8 words = 21.25 KB (fu halo)
#define FEH8 (NOCT * NPX)  // 1024 h8 words = 16 KB   (fe tile)
#define EPS_ 1e-12f

typedef _Float16 h2v __attribute__((ext_vector_type(2)));
typedef _Float16 h8v __attribute__((ext_vector_type(8)));

#if defined(__has_builtin)
#if __has_builtin(__builtin_amdgcn_fdot2)
#define HAVE_FDOT2 1
#endif
#if __has_builtin(__builtin_amdgcn_cvt_pkrtz)
#define HAVE_PKRTZ 1
#endif
#endif

static __device__ __forceinline__ h2v pk2(float a, float b) {
#if defined(HAVE_PKRTZ)
    return __builtin_bit_cast(h2v, __builtin_amdgcn_cvt_pkrtz(a, b));
#else
    h2v r = {(_Float16)a, (_Float16)b};
    return r;
#endif
}

static __device__ __forceinline__ float dot2(h2v a, h2v b, float c) {
#if defined(HAVE_FDOT2)
    return __builtin_amdgcn_fdot2(a, b, c, false);
#else
    return c + (float)a[0] * (float)b[0] + (float)a[1] * (float)b[1];
#endif
}

// R10 geometry (512 thr, 32x8 tile, 37.25 KB LDS -> 4 blocks/CU exact fill,
// grid 1024, launch_bounds(512,4) -> VGPR cap 64: the only non-spilling bound
// per the R2/R5/R8/R9 ledger) with oct-major h8 LDS layout:
//  - staging decodes (oct,pos) once per h8 WORD (2.66x/thread fu, 2x fe) vs
//    10.6x per h2v word in R10; one ds_write_b128 per unit.
//  - all taps are ds_read_b128 (8 channels/read): 40 DS reads/thread vs 76.
//  - border handling: clamped address + mask-multiply (no divergent branch).
__global__ __launch_bounds__(512, 4) void asfr_kernel(const float* __restrict__ fe,
                                                      const float* __restrict__ fu,
                                                      float* __restrict__ out) {
    __shared__ h8v lds8[FUH8 + FEH8];    // 38144 B
    const int t = threadIdx.x;
    const int bx = blockIdx.x & 7;           // W_/TX = 8
    const int by = (blockIdx.x >> 3) & 31;   // H_/TY = 32
    const int b  = blockIdx.x >> 8;
    const int w0 = bx * TX, h0 = by * TY;

    const float* fub = fu + b * (C_ * HW_);
    const float* feb = fe + b * (C_ * HW_);

    // ---- stage fu halo: unit = one h8 word (oct, pos); 1360 units, 3 rounds
#pragma unroll
    for (int j = 0; j < 3; ++j) {
        int u = t + j * 512;
        if (u < FUH8) {
            int oct = u / HCH;
            int pos = u - oct * HCH;
            int r = pos / HX;
            int col = pos - r * HX;
            int hh = h0 - 1 + r;
            int ww = w0 - 1 + col;
            bool ok = ((unsigned)hh < (unsigned)H_) && ((unsigned)ww < (unsigned)W_);
            int hcl = hh < 0 ? 0 : (hh > H_ - 1 ? H_ - 1 : hh);
            int wcl = ww < 0 ? 0 : (ww > W_ - 1 ? W_ - 1 : ww);
            const float* gp = fub + (oct * 8) * HW_ + hcl * W_ + wcl;
            float v[8];
#pragma unroll
            for (int c = 0; c < 8; ++c) v[c] = gp[c * HW_];
            float m = ok ? 1.f : 0.f;
#pragma unroll
            for (int c = 0; c < 8; ++c) v[c] *= m;
            h8v hv;
#pragma unroll
            for (int c = 0; c < 4; ++c) {
                h2v p = pk2(v[2 * c], v[2 * c + 1]);
                hv[2 * c] = p[0];
                hv[2 * c + 1] = p[1];
            }
            lds8[oct * HCH + pos] = hv;
        }
    }

    // ---- stage fe tile: unit = one h8 word (oct, px); 1024 units, 2 rounds
#pragma unroll
    for (int j = 0; j < 2; ++j) {
        int u = t + j * 512;
        int oct = u >> 8;
        int px = u & (NPX - 1);
        int hh = h0 + (px >> 5);
        int ww = w0 + (px & 31);
        const float* gp = feb + (oct * 8) * HW_ + hh * W_ + ww;
        float v[8];
#pragma unroll
        for (int c = 0; c < 8; ++c) v[c] = gp[c * HW_];
        h8v hv;
#pragma unroll
        for (int c = 0; c < 4; ++c) {
            h2v p = pk2(v[2 * c], v[2 * c + 1]);
            hv[2 * c] = p[0];
            hv[2 * c + 1] = p[1];
        }
        lds8[FUH8 + oct * NPX + px] = hv;
    }
    __syncthreads();

    const int x = t & 31;            // pixel x
    const int half = (t >> 5) & 1;   // channel half: octs 0-1 or 2-3
    const int y = t >> 6;            // pixel y (0..7)
    const int pxl = (y << 5) + x;
    const int pxoff = b * (C_ * HW_) + (h0 + y) * W_ + (w0 + x);
    const int hc = (y + 1) * HX + (x + 1);
    const int koff[K_] = {-HX - 1, -HX, -HX + 1, -1, 0, 1, HX - 1, HX, HX + 1};

    float dot[K_], psq[K_];
#pragma unroll
    for (int k = 0; k < K_; ++k) { dot[k] = 0.f; psq[k] = 0.f; }
    float fsq = 0.f;

    // Pass 1: per-k stats over this half's 2 octs; b128 taps, fdot2 f32-accum
#pragma unroll
    for (int j = 0; j < 2; ++j) {
        const int oct = 2 * half + j;
        h8v fq = lds8[FUH8 + oct * NPX + pxl];
        h2v fA0 = __builtin_shufflevector(fq, fq, 0, 1);
        h2v fA1 = __builtin_shufflevector(fq, fq, 2, 3);
        h2v fA2 = __builtin_shufflevector(fq, fq, 4, 5);
        h2v fA3 = __builtin_shufflevector(fq, fq, 6, 7);
        fsq = dot2(fA0, fA0, fsq);
        fsq = dot2(fA1, fA1, fsq);
        fsq = dot2(fA2, fA2, fsq);
        fsq = dot2(fA3, fA3, fsq);
        const h8v* fubase = &lds8[oct * HCH + hc];
#pragma unroll
        for (int k = 0; k < K_; ++k) {
            h8v p8 = fubase[koff[k]];
            h2v p0 = __builtin_shufflevector(p8, p8, 0, 1);
            h2v p1 = __builtin_shufflevector(p8, p8, 2, 3);
            h2v p2 = __builtin_shufflevector(p8, p8, 4, 5);
            h2v p3 = __builtin_shufflevector(p8, p8, 6, 7);
            dot[k] = dot2(p0, fA0, dot[k]);
            dot[k] = dot2(p1, fA1, dot[k]);
            dot[k] = dot2(p2, fA2, dot[k]);
            dot[k] = dot2(p3, fA3, dot[k]);
            psq[k] = dot2(p0, p0, psq[k]);
            psq[k] = dot2(p1, p1, psq[k]);
            psq[k] = dot2(p2, p2, psq[k]);
            psq[k] = dot2(p3, p3, psq[k]);
        }
    }

    // combine halves: lanes l and l^32 hold the two channel-halves of one pixel
#pragma unroll
    for (int k = 0; k < K_; ++k) {
        dot[k] += __shfl_xor(dot[k], 32);
        psq[k] += __shfl_xor(psq[k], 32);
    }
    fsq += __shfl_xor(fsq, 32);

    float nf = fmaxf(sqrtf(fsq), EPS_);
    float cosv[K_], negd[K_];
#pragma unroll
    for (int k = 0; k < K_; ++k) {
        float np = fmaxf(sqrtf(psq[k]), EPS_);
        cosv[k] = __fdividef(dot[k], np * nf);
        float dsq = fmaxf(psq[k] - 2.f * dot[k] + fsq, 0.f);   // ||p-f||^2
        negd[k] = -sqrtf(dsq);
    }

    float m1 = cosv[0], m2 = negd[0];
#pragma unroll
    for (int k = 1; k < K_; ++k) { m1 = fmaxf(m1, cosv[k]); m2 = fmaxf(m2, negd[k]); }
    float s1 = 0.f, s2 = 0.f, e1[K_], e2[K_];
#pragma unroll
    for (int k = 0; k < K_; ++k) {
        e1[k] = __expf(cosv[k] - m1);
        e2[k] = __expf(negd[k] - m2);
        s1 += e1[k]; s2 += e2[k];
    }
    float r1 = __fdividef(0.5f, s1), r2 = __fdividef(0.5f, s2);
    h2v w2[K_];
#pragma unroll
    for (int k = 0; k < K_; ++k) {
        float wk = fmaf(e1[k], r1, e2[k] * r2);
        _Float16 wh = (_Float16)wk;
        h2v tmp = {wh, wh};
        w2[k] = tmp;
    }

    // Pass 2: packed weighted gather (b128 taps) + f16 residual + store
#pragma unroll
    for (int j = 0; j < 2; ++j) {
        const int oct = 2 * half + j;
        const h8v* fubase = &lds8[oct * HCH + hc];
        h2v a0 = {(_Float16)0, (_Float16)0};
        h2v a1 = a0, a2 = a0, a3 = a0;
#pragma unroll
        for (int k = 0; k < K_; ++k) {
            h8v p8 = fubase[koff[k]];
            a0 += w2[k] * __builtin_shufflevector(p8, p8, 0, 1);
            a1 += w2[k] * __builtin_shufflevector(p8, p8, 2, 3);
            a2 += w2[k] * __builtin_shufflevector(p8, p8, 4, 5);
            a3 += w2[k] * __builtin_shufflevector(p8, p8, 6, 7);
        }
        h8v fq = lds8[FUH8 + oct * NPX + pxl];
        const int cg = oct * 8;
        out[pxoff + (cg + 0) * HW_] = (float)(fq[0] + a0[0]);
        out[pxoff + (cg + 1) * HW_] = (float)(fq[1] + a0[1]);
        out[pxoff + (cg + 2) * HW_] = (float)(fq[2] + a1[0]);
        out[pxoff + (cg + 3) * HW_] = (float)(fq[3] + a1[1]);
        out[pxoff + (cg + 4) * HW_] = (float)(fq[4] + a2[0]);
        out[pxoff + (cg + 5) * HW_] = (float)(fq[5] + a2[1]);
        out[pxoff + (cg + 6) * HW_] = (float)(fq[6] + a3[0]);
        out[pxoff + (cg + 7) * HW_] = (float)(fq[7] + a3[1]);
    }
}

extern "C" void kernel_launch(void* const* d_in, const int* in_sizes, int n_in,
                              void* d_out, int out_size, void* d_ws, size_t ws_size,
                              hipStream_t stream) {
    const float* fe = (const float*)d_in[0];
    const float* fu = (const float*)d_in[1];
    float* out = (float*)d_out;
    dim3 grid((W_ / TX) * (H_ / TY) * B_), block(512);  // 1024 blocks = 4/CU exact
    hipLaunchKernelGGL(asfr_kernel, grid, block, 0, stream, fe, fu, out);
}